// Round 9
// baseline (1343.876 us; speedup 1.0000x reference)
//
#include <hip/hip_runtime.h>
#include <math.h>

// Static problem dims
#define NG 64          // graphs
#define EE 64000       // edges
#define HC3 3072       // H*C
#define CC 1024        // C (and input feature dim)
#define MAXDEG 64      // fixed CSR stride (Poisson(5) in-degree; P(>64) ~ 1e-60)

static inline int cdiv(int a, int b) { return (a + b - 1) / b; }

typedef float f4_t __attribute__((ext_vector_type(4)));
typedef short s8_t __attribute__((ext_vector_type(8)));

__device__ __forceinline__ float lrelu(float x) { return x > 0.f ? x : 0.2f * x; }
__device__ __forceinline__ unsigned fenc(float f) {
    unsigned u = __float_as_uint(f);
    return (u & 0x80000000u) ? ~u : (u | 0x80000000u);
}
__device__ __forceinline__ float fdec(unsigned e) {
    return (e & 0x80000000u) ? __uint_as_float(e ^ 0x80000000u) : __uint_as_float(~e);
}
__device__ __forceinline__ unsigned short f2bf(float f) {
    unsigned u = __float_as_uint(f);
    u += 0x7fffu + ((u >> 16) & 1u);
    return (unsigned short)(u >> 16);
}
__device__ __forceinline__ float bf2f(unsigned short h) {
    return __uint_as_float(((unsigned)h) << 16);
}
__device__ __forceinline__ void gll16(const unsigned short* g, unsigned short* l) {
    __builtin_amdgcn_global_load_lds(
        (const __attribute__((address_space(1))) void*)g,
        (__attribute__((address_space(3))) void*)l, 16, 0, 0);
}

// ======== prep GEMM: C = A @ B^T per slot; epilogue writes split-bf16 B2 interleaved ========
__global__ __launch_bounds__(256) void gemm_prep(
    const unsigned short* __restrict__ Ahi, const unsigned short* __restrict__ Alo,
    const unsigned short* __restrict__ Bhi, const unsigned short* __restrict__ Blo,
    unsigned short* __restrict__ ohi, unsigned short* __restrict__ olo, int K)
{
    __shared__ unsigned short sAH[128 * 32];
    __shared__ unsigned short sAL[128 * 32];
    __shared__ unsigned short sBH[128 * 32];
    __shared__ unsigned short sBL[128 * 32];

    const size_t MSZ = (size_t)CC * CC;
    const int slot = blockIdx.z;
    const int lrel = slot / 3, hh = slot % 3;
    Ahi += slot * MSZ; Alo += slot * MSZ;
    Bhi += slot * MSZ; Blo += slot * MSZ;

    const int t = threadIdx.x;
    const int w = t >> 6, lane = t & 63;
    const int wr = w >> 1, wc = w & 1;
    const int row0 = blockIdx.y * 128, col0 = blockIdx.x * 128;

    const int srow = w * 16 + (lane >> 2);
    const int skg = (((lane & 3) ^ ((lane >> 3) & 3)) << 3);
    const size_t aoff0 = (size_t)(row0 + srow) * CC + skg;
    const size_t aoff1 = (size_t)(row0 + 64 + srow) * CC + skg;
    const size_t boff0 = (size_t)(col0 + srow) * CC + skg;
    const size_t boff1 = (size_t)(col0 + 64 + srow) * CC + skg;
    const int l0 = (w * 16) * 32;
    const int l1 = (64 + w * 16) * 32;

    f4_t acc[4][4];
    const f4_t z4 = {0.f, 0.f, 0.f, 0.f};
#pragma unroll
    for (int i = 0; i < 4; ++i)
#pragma unroll
        for (int j = 0; j < 4; ++j) acc[i][j] = z4;

    const int mrow0 = wr * 64 + (lane & 15);
    const int nrow0 = wc * 64 + (lane & 15);
    const int kslot = (((lane >> 4) ^ ((lane >> 1) & 3)) << 3);

    for (int k0 = 0; k0 < K; k0 += 32) {
        gll16(Ahi + aoff0 + k0, &sAH[l0]);
        gll16(Ahi + aoff1 + k0, &sAH[l1]);
        gll16(Alo + aoff0 + k0, &sAL[l0]);
        gll16(Alo + aoff1 + k0, &sAL[l1]);
        gll16(Bhi + boff0 + k0, &sBH[l0]);
        gll16(Bhi + boff1 + k0, &sBH[l1]);
        gll16(Blo + boff0 + k0, &sBL[l0]);
        gll16(Blo + boff1 + k0, &sBL[l1]);
        __syncthreads();

        s8_t ah[4], al[4], bh[4], bl[4];
#pragma unroll
        for (int mt = 0; mt < 4; ++mt) {
            ah[mt] = *(const s8_t*)&sAH[(mrow0 + mt * 16) * 32 + kslot];
            al[mt] = *(const s8_t*)&sAL[(mrow0 + mt * 16) * 32 + kslot];
        }
#pragma unroll
        for (int nt = 0; nt < 4; ++nt) {
            bh[nt] = *(const s8_t*)&sBH[(nrow0 + nt * 16) * 32 + kslot];
            bl[nt] = *(const s8_t*)&sBL[(nrow0 + nt * 16) * 32 + kslot];
        }
#pragma unroll
        for (int mt = 0; mt < 4; ++mt)
#pragma unroll
            for (int nt = 0; nt < 4; ++nt) {
                acc[mt][nt] = __builtin_amdgcn_mfma_f32_16x16x32_bf16(ah[mt], bh[nt], acc[mt][nt], 0, 0, 0);
                acc[mt][nt] = __builtin_amdgcn_mfma_f32_16x16x32_bf16(ah[mt], bl[nt], acc[mt][nt], 0, 0, 0);
                acc[mt][nt] = __builtin_amdgcn_mfma_f32_16x16x32_bf16(al[mt], bh[nt], acc[mt][nt], 0, 0, 0);
            }
        __syncthreads();
    }

#pragma unroll
    for (int mt = 0; mt < 4; ++mt) {
        int row = row0 + wr * 64 + mt * 16 + (lane >> 4) * 4;
#pragma unroll
        for (int nt = 0; nt < 4; ++nt) {
            int col = col0 + wc * 64 + nt * 16 + (lane & 15);
#pragma unroll
            for (int r = 0; r < 4; ++r) {
                float v = acc[mt][nt][r];
                unsigned short hv = f2bf(v);
                size_t dst = (size_t)lrel * 3 * MSZ + (size_t)(row + r) * HC3 + hh * CC + col;
                ohi[dst] = hv;
                olo[dst] = f2bf(v - bf2f(hv));
            }
        }
    }
}

// ======== main GEMM: split-K + L2-friendly grid, fp32 atomicAdd into zeroed C ========
__global__ __launch_bounds__(256) void gemm_splitk(
    const unsigned short* __restrict__ Ahi, const unsigned short* __restrict__ Alo, int lda,
    const unsigned short* __restrict__ Bhi, const unsigned short* __restrict__ Blo, int ldb,
    float* __restrict__ C, int ldc, int ksub)
{
    __shared__ unsigned short sAH[128 * 32];
    __shared__ unsigned short sAL[128 * 32];
    __shared__ unsigned short sBH[128 * 32];
    __shared__ unsigned short sBL[128 * 32];

    const int t = threadIdx.x;
    const int w = t >> 6, lane = t & 63;
    const int wr = w >> 1, wc = w & 1;
    const int row0 = blockIdx.x * 128, col0 = blockIdx.y * 128;
    const int kbase = blockIdx.z * ksub;

    const int srow = w * 16 + (lane >> 2);
    const int skg = (((lane & 3) ^ ((lane >> 3) & 3)) << 3);
    const size_t aoff0 = (size_t)(row0 + srow) * lda + skg;
    const size_t aoff1 = (size_t)(row0 + 64 + srow) * lda + skg;
    const size_t boff0 = (size_t)(col0 + srow) * ldb + skg;
    const size_t boff1 = (size_t)(col0 + 64 + srow) * ldb + skg;
    const int l0 = (w * 16) * 32;
    const int l1 = (64 + w * 16) * 32;

    f4_t acc[4][4];
    const f4_t z4 = {0.f, 0.f, 0.f, 0.f};
#pragma unroll
    for (int i = 0; i < 4; ++i)
#pragma unroll
        for (int j = 0; j < 4; ++j) acc[i][j] = z4;

    const int mrow0 = wr * 64 + (lane & 15);
    const int nrow0 = wc * 64 + (lane & 15);
    const int kslot = (((lane >> 4) ^ ((lane >> 1) & 3)) << 3);

    for (int k0 = kbase; k0 < kbase + ksub; k0 += 32) {
        gll16(Ahi + aoff0 + k0, &sAH[l0]);
        gll16(Ahi + aoff1 + k0, &sAH[l1]);
        gll16(Alo + aoff0 + k0, &sAL[l0]);
        gll16(Alo + aoff1 + k0, &sAL[l1]);
        gll16(Bhi + boff0 + k0, &sBH[l0]);
        gll16(Bhi + boff1 + k0, &sBH[l1]);
        gll16(Blo + boff0 + k0, &sBL[l0]);
        gll16(Blo + boff1 + k0, &sBL[l1]);
        __syncthreads();

        s8_t ah[4], al[4], bh[4], bl[4];
#pragma unroll
        for (int mt = 0; mt < 4; ++mt) {
            ah[mt] = *(const s8_t*)&sAH[(mrow0 + mt * 16) * 32 + kslot];
            al[mt] = *(const s8_t*)&sAL[(mrow0 + mt * 16) * 32 + kslot];
        }
#pragma unroll
        for (int nt = 0; nt < 4; ++nt) {
            bh[nt] = *(const s8_t*)&sBH[(nrow0 + nt * 16) * 32 + kslot];
            bl[nt] = *(const s8_t*)&sBL[(nrow0 + nt * 16) * 32 + kslot];
        }
#pragma unroll
        for (int mt = 0; mt < 4; ++mt)
#pragma unroll
            for (int nt = 0; nt < 4; ++nt) {
                acc[mt][nt] = __builtin_amdgcn_mfma_f32_16x16x32_bf16(ah[mt], bh[nt], acc[mt][nt], 0, 0, 0);
                acc[mt][nt] = __builtin_amdgcn_mfma_f32_16x16x32_bf16(ah[mt], bl[nt], acc[mt][nt], 0, 0, 0);
                acc[mt][nt] = __builtin_amdgcn_mfma_f32_16x16x32_bf16(al[mt], bh[nt], acc[mt][nt], 0, 0, 0);
            }
        __syncthreads();
    }

#pragma unroll
    for (int mt = 0; mt < 4; ++mt) {
        int row = row0 + wr * 64 + mt * 16 + (lane >> 4) * 4;
#pragma unroll
        for (int nt = 0; nt < 4; ++nt) {
            int col = col0 + wc * 64 + nt * 16 + (lane & 15);
#pragma unroll
            for (int r = 0; r < 4; ++r)
                atomicAdd(&C[(size_t)(row + r) * ldc + col], acc[mt][nt][r]);
        }
    }
}

// ---- weight prep ----
__global__ void split_w_all(const float* __restrict__ w0, const float* __restrict__ w1,
    const float* __restrict__ w2, int lbase,
    unsigned short* __restrict__ ohi, unsigned short* __restrict__ olo)
{
    const float* Wp[3] = {w0, w1, w2};
    int slot = blockIdx.y;
    int L = lbase + slot / 3, h = slot % 3;
    int idx = blockIdx.x * 256 + threadIdx.x;
    int r = idx >> 10, c = idx & 1023;
    float v = Wp[L][(size_t)r * HC3 + h * CC + c];
    unsigned short hh = f2bf(v);
    ohi[(size_t)slot * 1048576 + idx] = hh;
    olo[(size_t)slot * 1048576 + idx] = f2bf(v - bf2f(hh));
}

__global__ void transpose_split_wt_all(const float* __restrict__ w0,
    const float* __restrict__ w1, const float* __restrict__ w2, int lbase,
    unsigned short* __restrict__ ohi, unsigned short* __restrict__ olo)
{
    const float* Wp[3] = {w0, w1, w2};
    int slot = blockIdx.z;
    int L = lbase + slot / 3, h = slot % 3;
    __shared__ float tile[32][33];
    int t = threadIdx.x, tr = t >> 5, tc = t & 31;
    int r0 = blockIdx.y * 32, c0 = blockIdx.x * 32;
    const float* in = Wp[L] + (size_t)h * 1048576;
#pragma unroll
    for (int i = 0; i < 4; ++i)
        tile[tr + i * 8][tc] = in[(size_t)(r0 + tr + i * 8) * CC + c0 + tc];
    __syncthreads();
    unsigned short* oh = ohi + (size_t)slot * 1048576;
    unsigned short* ol = olo + (size_t)slot * 1048576;
#pragma unroll
    for (int i = 0; i < 4; ++i) {
        int oc = c0 + tr + i * 8;
        int orr = r0 + tc;
        float v = tile[tc][tr + i * 8];
        unsigned short hh = f2bf(v);
        oh[(size_t)oc * CC + orr] = hh;
        ol[(size_t)oc * CC + orr] = f2bf(v - bf2f(hh));
    }
}

// ---- u[L][h*CC+m] = Wt_L row (h*CC+m) . p_L ----
__global__ __launch_bounds__(256) void wtp_all(const float* __restrict__ wt0,
    const float* __restrict__ wt1, const float* __restrict__ wt2,
    const float* __restrict__ p0, const float* __restrict__ p1, const float* __restrict__ p2,
    int lbase, float* __restrict__ U)
{
    const float* Wp[3] = {wt0, wt1, wt2};
    const float* Pp[3] = {p0, p1, p2};
    int wid = blockIdx.x * 4 + (threadIdx.x >> 6);
    int lane = threadIdx.x & 63;
    int L = lbase + wid / HC3, rr = wid % HC3;
    const float* row = Wp[L] + (size_t)rr * CC;
    const float* p = Pp[L];
    float s = 0.f;
    for (int c = lane; c < CC; c += 64) s += row[c] * p[c];
    for (int off = 32; off; off >>= 1) s += __shfl_xor(s, off, 64);
    if (lane == 0) U[(size_t)L * HC3 + rr] = s;
}

// ---- attention helper vectors + q (q_h = W_h u_h) ----
__global__ __launch_bounds__(256) void attvec_all(const float* __restrict__ w0,
    const float* __restrict__ w1, const float* __restrict__ w2,
    const float* __restrict__ as0, const float* __restrict__ as1, const float* __restrict__ as2,
    const float* __restrict__ ad0, const float* __restrict__ ad1, const float* __restrict__ ad2,
    const float* __restrict__ U, int lbase,
    float* __restrict__ asv, float* __restrict__ adv, float* __restrict__ qv)
{
    const float* Wp[3] = {w0, w1, w2};
    const float* Sp[3] = {as0, as1, as2};
    const float* Dp[3] = {ad0, ad1, ad2};
    int L = lbase + blockIdx.y;
    int wid = blockIdx.x * 4 + (threadIdx.x >> 6);
    int lane = threadIdx.x & 63;
    int h = wid >> 10, kk = wid & 1023;
    const float* wr = Wp[L] + (long long)kk * HC3 + h * CC;
    const float* sa = Sp[L] + h * CC;
    const float* da = Dp[L] + h * CC;
    const float* ua = U + (size_t)L * HC3 + h * CC;
    float ss = 0.f, dd = 0.f, qq = 0.f;
    for (int c = lane; c < CC; c += 64) {
        float w = wr[c];
        ss += w * sa[c]; dd += w * da[c]; qq += w * ua[c];
    }
    for (int off = 32; off; off >>= 1) {
        ss += __shfl_xor(ss, off, 64); dd += __shfl_xor(dd, off, 64); qq += __shfl_xor(qq, off, 64);
    }
    if (lane == 0) {
        asv[(size_t)L * HC3 + h * CC + kk] = ss;
        adv[(size_t)L * HC3 + h * CC + kk] = dd;
        qv[(size_t)L * HC3 + h * CC + kk] = qq;
    }
}

// ---- per-node: a_s, a_d, t dots + node init ----
__global__ __launch_bounds__(256) void attn_node(const float* __restrict__ xin,
    const float* __restrict__ asv, const float* __restrict__ adv, const float* __restrict__ q,
    float* __restrict__ AS, float* __restrict__ AD, float* __restrict__ T3,
    float* __restrict__ sl, unsigned* __restrict__ mxe, float* __restrict__ sexp,
    int* __restrict__ cnt, int n)
{
    int node = blockIdx.x * 4 + (threadIdx.x >> 6);
    int lane = threadIdx.x & 63;
    if (node >= n) return;
    const float* xr = xin + (long long)node * CC;
    float s0 = 0, s1 = 0, s2 = 0, d0 = 0, d1 = 0, d2 = 0, t0 = 0, t1 = 0, t2 = 0;
    for (int j = lane; j < CC; j += 64) {
        float v = xr[j];
        s0 += v * asv[j]; s1 += v * asv[CC + j]; s2 += v * asv[2 * CC + j];
        d0 += v * adv[j]; d1 += v * adv[CC + j]; d2 += v * adv[2 * CC + j];
        t0 += v * q[j];   t1 += v * q[CC + j];   t2 += v * q[2 * CC + j];
    }
    for (int off = 32; off; off >>= 1) {
        s0 += __shfl_xor(s0, off, 64); s1 += __shfl_xor(s1, off, 64); s2 += __shfl_xor(s2, off, 64);
        d0 += __shfl_xor(d0, off, 64); d1 += __shfl_xor(d1, off, 64); d2 += __shfl_xor(d2, off, 64);
        t0 += __shfl_xor(t0, off, 64); t1 += __shfl_xor(t1, off, 64); t2 += __shfl_xor(t2, off, 64);
    }
    if (lane == 0) {
        AS[node * 3 + 0] = s0; AS[node * 3 + 1] = s1; AS[node * 3 + 2] = s2;
        AD[node * 3 + 0] = d0; AD[node * 3 + 1] = d1; AD[node * 3 + 2] = d2;
        T3[node * 3 + 0] = t0; T3[node * 3 + 1] = t1; T3[node * 3 + 2] = t2;
        float l0v = lrelu(s0 + d0), l1v = lrelu(s1 + d1), l2v = lrelu(s2 + d2);
        sl[node * 3 + 0] = l0v; sl[node * 3 + 1] = l1v; sl[node * 3 + 2] = l2v;
        mxe[node * 3 + 0] = fenc(l0v); mxe[node * 3 + 1] = fenc(l1v); mxe[node * 3 + 2] = fenc(l2v);
        sexp[node * 3 + 0] = 0.f; sexp[node * 3 + 1] = 0.f; sexp[node * 3 + 2] = 0.f;
        cnt[node] = 0;
    }
}

// ---- BV init + pnorm ----
__global__ void bvinit_pnorm(const float* __restrict__ bt0, const float* __restrict__ bt1,
    const float* __restrict__ bt2, const float* __restrict__ p0, const float* __restrict__ p1,
    const float* __restrict__ p2, int lbase, float* __restrict__ BV, float* __restrict__ PN)
{
    const float* Bp[3] = {bt0, bt1, bt2};
    const float* Pp[3] = {p0, p1, p2};
    int L = lbase + blockIdx.y;
    if (blockIdx.x < 4) {
        int c = blockIdx.x * 256 + threadIdx.x;
        BV[(size_t)L * CC + c] = Bp[L][c];
    } else {
        __shared__ float red[256];
        int t = threadIdx.x;
        const float* p = Pp[L];
        float s = 0.f;
        for (int j = t; j < CC; j += 256) { float v = p[j]; s += v * v; }
        red[t] = s; __syncthreads();
        for (int off = 128; off; off >>= 1) { if (t < off) red[t] += red[t + off]; __syncthreads(); }
        if (t == 0) PN[L] = sqrtf(red[0]);
    }
}

__global__ void bvec_part(const float* __restrict__ b0, const float* __restrict__ b1,
    const float* __restrict__ b2, const float* __restrict__ wt0, const float* __restrict__ wt1,
    const float* __restrict__ wt2, int lbase, float* __restrict__ BV)
{
    const float* bp[3] = {b0, b1, b2};
    const float* wp[3] = {wt0, wt1, wt2};
    int L = lbase + blockIdx.z;
    int c = blockIdx.x * 256 + threadIdx.x;
    int k0 = blockIdx.y * 256;
    const float* b = bp[L];
    const float* Wt = wp[L];
    float acc = 0.f;
#pragma unroll 8
    for (int k = k0; k < k0 + 256; ++k) acc += b[k] * Wt[(size_t)k * CC + c];
    atomicAdd(&BV[(size_t)L * CC + c], acc);
}

__global__ void bvp_all(const float* __restrict__ BV, const float* __restrict__ p0,
    const float* __restrict__ p1, const float* __restrict__ p2, int lbase,
    float* __restrict__ BVP)
{
    const float* Pp[3] = {p0, p1, p2};
    int L = lbase + blockIdx.x;
    __shared__ float red[256];
    int t = threadIdx.x;
    const float* p = Pp[L];
    float s = 0.f;
    for (int j = t; j < CC; j += 256) s += BV[(size_t)L * CC + j] * p[j];
    red[t] = s; __syncthreads();
    for (int off = 128; off; off >>= 1) { if (t < off) red[t] += red[t + off]; __syncthreads(); }
    if (t == 0) BVP[L] = red[0];
}

// ---- fused edge pass: optional remap + count + fixed-stride CSR fill + max + exp-sum ----
__global__ void edge_pass1(int* __restrict__ src, int* __restrict__ dst,
    int* __restrict__ msk, const int* __restrict__ newid,
    const float* __restrict__ AS, const float* __restrict__ AD,
    unsigned* __restrict__ mxe, float* __restrict__ sexp, int* __restrict__ cnt,
    int* __restrict__ csrs)
{
    int e = blockIdx.x * 256 + threadIdx.x;
    if (e >= EE) return;
    int m = msk[e];
    int s, d;
    if (newid) {
        if (!m) { src[e] = 0; dst[e] = 0; return; }
        int ns = newid[src[e]], nd = newid[dst[e]];
        int nm = (ns >= 0 && nd >= 0) ? 1 : 0;
        msk[e] = nm; src[e] = nm ? ns : 0; dst[e] = nm ? nd : 0;
        if (!nm) return;
        s = ns; d = nd;
    } else {
        if (!m) return;
        s = src[e]; d = dst[e];
    }
    int slot = atomicAdd(&cnt[d], 1);
    if (slot < MAXDEG) csrs[d * MAXDEG + slot] = s;
#pragma unroll
    for (int h = 0; h < 3; ++h) {
        float l = lrelu(AS[s * 3 + h] + AD[d * 3 + h]);
        atomicMax(&mxe[d * 3 + h], fenc(l));
        atomicAdd(&sexp[d * 3 + h], expf(l));
    }
}

// ---- fused score (on-the-fly softmax over fixed CSR) + topk per graph ----
__global__ __launch_bounds__(64) void score_topk(const float* __restrict__ T3,
    const float* __restrict__ sl, const unsigned* __restrict__ mxe,
    const float* __restrict__ sexp, const float* __restrict__ AS,
    const float* __restrict__ AD, const int* __restrict__ cnt, const int* __restrict__ csrs,
    const float* __restrict__ bvp, const float* __restrict__ pn,
    int npg, int k, int* __restrict__ perm, float* __restrict__ vals, int* __restrict__ newid)
{
    __shared__ float sc[256];
    int g = blockIdx.x, lane = threadIdx.x;
    float bv0 = bvp[0], pn0 = pn[0];
    for (int ii = lane; ii < npg; ii += 64) {
        int i = g * npg + ii;
        float s = 0.f;
        float mxf3[3], rden3[3], ad3[3];
#pragma unroll
        for (int h = 0; h < 3; ++h) {
            float m = fdec(mxe[i * 3 + h]);
            float es = expf(sl[i * 3 + h] - m);
            float den = es + expf(-m) * sexp[i * 3 + h];
            mxf3[h] = m; rden3[h] = 1.f / (den + 1e-16f);
            ad3[h] = AD[i * 3 + h];
            s += es * rden3[h] * T3[i * 3 + h];
        }
        int num = cnt[i]; if (num > MAXDEG) num = MAXDEG;
        int beg = i * MAXDEG;
        for (int e = 0; e < num; ++e) {
            int sn = csrs[beg + e];
#pragma unroll
            for (int h = 0; h < 3; ++h) {
                float l = lrelu(AS[sn * 3 + h] + ad3[h]);
                s += expf(l - mxf3[h]) * rden3[h] * T3[sn * 3 + h];
            }
        }
        sc[ii] = tanhf((s + bv0) / pn0);
        newid[i] = -1;
    }
    __syncthreads();
    float v[4];
    int nsl = (npg + 63) >> 6;
#pragma unroll
    for (int s2 = 0; s2 < 4; ++s2) {
        int idx = lane + (s2 << 6);
        v[s2] = (s2 < nsl && idx < npg) ? sc[idx] : -1e30f;
    }
    for (int j = 0; j < k; ++j) {
        float bv = -2e30f; int bi = 0x7fffffff;
#pragma unroll
        for (int s2 = 0; s2 < 4; ++s2) {
            int idx = lane + (s2 << 6);
            if (v[s2] > bv) { bv = v[s2]; bi = idx; }
        }
        for (int off = 32; off; off >>= 1) {
            float ov = __shfl_xor(bv, off, 64);
            int   oi = __shfl_xor(bi, off, 64);
            if (ov > bv || (ov == bv && oi < bi)) { bv = ov; bi = oi; }
        }
        if (lane == 0) {
            perm[g * k + j] = g * npg + bi;
            vals[g * k + j] = bv;
            newid[g * npg + bi] = g * k + j;
        }
        if ((bi & 63) == lane) v[bi >> 6] = -1e30f;
    }
}

// ---- aggregation of SELECTED rows, alphas staged in LDS, concat split-bf16 out ----
__global__ __launch_bounds__(256) void aggregate_sel(const float* __restrict__ xin,
    const float* __restrict__ sl, const unsigned* __restrict__ mxe,
    const float* __restrict__ sexp, const float* __restrict__ AS,
    const float* __restrict__ AD, const int* __restrict__ cnt, const int* __restrict__ csrs,
    const int* __restrict__ perm,
    unsigned short* __restrict__ ahi, unsigned short* __restrict__ alo)
{
    __shared__ float salpha[MAXDEG * 3];
    __shared__ int ssrc[MAXDEG];
    int r = blockIdx.x, t = threadIdx.x;
    int i = perm[r];
    float mxf3[3], rden3[3], aself[3];
#pragma unroll
    for (int h = 0; h < 3; ++h) {
        float m = fdec(mxe[i * 3 + h]);
        float es = expf(sl[i * 3 + h] - m);
        float den = es + expf(-m) * sexp[i * 3 + h];
        mxf3[h] = m; rden3[h] = 1.f / (den + 1e-16f);
        aself[h] = es * rden3[h];
    }
    int num = cnt[i]; if (num > MAXDEG) num = MAXDEG;
    if (t < num) {
        int sn = csrs[i * MAXDEG + t];
        ssrc[t] = sn;
#pragma unroll
        for (int h = 0; h < 3; ++h) {
            float l = lrelu(AS[sn * 3 + h] + AD[i * 3 + h]);
            salpha[t * 3 + h] = expf(l - mxf3[h]) * rden3[h];
        }
    }
    __syncthreads();
    const float* xr = xin + (long long)i * CC;
    float acc[3][4];
#pragma unroll
    for (int j = 0; j < 4; ++j) {
        float v = xr[t + (j << 8)];
#pragma unroll
        for (int h = 0; h < 3; ++h) acc[h][j] = aself[h] * v;
    }
    for (int e = 0; e < num; ++e) {
        int s = ssrc[e];
        float a0 = salpha[e * 3 + 0];
        float a1 = salpha[e * 3 + 1];
        float a2 = salpha[e * 3 + 2];
        const float* sr = xin + (long long)s * CC;
#pragma unroll
        for (int j = 0; j < 4; ++j) {
            float v = sr[t + (j << 8)];
            acc[0][j] += a0 * v; acc[1][j] += a1 * v; acc[2][j] += a2 * v;
        }
    }
#pragma unroll
    for (int h = 0; h < 3; ++h)
#pragma unroll
        for (int j = 0; j < 4; ++j) {
            int c = t + (j << 8);
            float v = acc[h][j];
            unsigned short hh = f2bf(v);
            size_t idx = (size_t)r * HC3 + h * CC + c;
            ahi[idx] = hh;
            alo[idx] = f2bf(v - bf2f(hh));
        }
}

// ---- readout pass 1 with fused finalize: xn = (xn + BV) * vals[row] ----
__global__ __launch_bounds__(256) void readout_part(float* __restrict__ xn,
    const float* __restrict__ BV, const float* __restrict__ vals,
    int k, float* __restrict__ PM, float* __restrict__ PS)
{
    int g = blockIdx.x, ch = blockIdx.y, t = threadIdx.x;
    int rpc = k >> 3, r0 = ch * rpc;
#pragma unroll
    for (int j = 0; j < 4; ++j) {
        int c = t + (j << 8);
        float bvc = BV[c];
        float mx = -1e30f, sm = 0.f;
        for (int r = r0; r < r0 + rpc; ++r) {
            size_t idx = ((size_t)(g * k + r)) * CC + c;
            float vv = (xn[idx] + bvc) * vals[g * k + r];
            xn[idx] = vv;
            mx = fmaxf(mx, vv); sm += vv;
        }
        PM[(size_t)(g * 8 + ch) * CC + c] = mx;
        PS[(size_t)(g * 8 + ch) * CC + c] = sm;
    }
}

__global__ __launch_bounds__(256) void readout_fin(const float* __restrict__ PM,
    const float* __restrict__ PS, int k, float* __restrict__ R)
{
    int g = blockIdx.x, t = threadIdx.x;
#pragma unroll
    for (int j = 0; j < 4; ++j) {
        int c = t + (j << 8);
        float mx = -1e30f, sm = 0.f;
#pragma unroll
        for (int ch = 0; ch < 8; ++ch) {
            mx = fmaxf(mx, PM[(size_t)(g * 8 + ch) * CC + c]);
            sm += PS[(size_t)(g * 8 + ch) * CC + c];
        }
        R[g * 2048 + c] = mx;
        R[g * 2048 + 1024 + c] = sm / (float)k;
    }
}

__global__ void copy_edges(const int* __restrict__ ei, int* __restrict__ s,
    int* __restrict__ d, int* __restrict__ m)
{
    int e = blockIdx.x * 256 + threadIdx.x;
    if (e >= EE) return;
    s[e] = ei[e]; d[e] = ei[EE + e]; m[e] = 1;
}

// ---------------- final MLP ----------------
__global__ __launch_bounds__(256) void mlp1_kernel(const float* __restrict__ R0,
    const float* __restrict__ R1, const float* __restrict__ R2,
    const float* __restrict__ Wl1, const float* __restrict__ bl1, float* __restrict__ Z1)
{
    int c = blockIdx.x * 256 + threadIdx.x;
    int g = blockIdx.y;
    float acc = bl1[c];
    const float* r0 = R0 + g * 2048;
    const float* r1 = R1 + g * 2048;
    const float* r2 = R2 + g * 2048;
    for (int kk = 0; kk < 2048; ++kk)
        acc += (r0[kk] + r1[kk] + r2[kk]) * Wl1[kk * 1024 + c];
    Z1[g * 1024 + c] = acc > 0.f ? acc : 0.f;
}

__global__ __launch_bounds__(64) void mlp2_kernel(const float* __restrict__ Z1,
    const float* __restrict__ Wl2, const float* __restrict__ bl2, float* __restrict__ out)
{
    int b = blockIdx.x; int g = b >> 1, o = b & 1;
    int lane = threadIdx.x;
    const float* zr = Z1 + g * 1024;
    float s = 0.f;
    for (int j = lane; j < 1024; j += 64) s += zr[j] * Wl2[j * 2 + o];
    for (int off = 32; off; off >>= 1) s += __shfl_xor(s, off, 64);
    if (lane == 0) out[g * 2 + o] = s + bl2[o];
}

// ---------------- host ----------------
extern "C" void kernel_launch(void* const* d_in, const int* in_sizes, int n_in,
                              void* d_out, int out_size, void* d_ws, size_t ws_size,
                              hipStream_t stream)
{
    const float* x   = (const float*)d_in[0];
    const int*   ei  = (const int*)d_in[2];
    const float* W[3]    = {(const float*)d_in[4],  (const float*)d_in[11], (const float*)d_in[18]};
    const float* atts[3] = {(const float*)d_in[5],  (const float*)d_in[12], (const float*)d_in[19]};
    const float* attd[3] = {(const float*)d_in[6],  (const float*)d_in[13], (const float*)d_in[20]};
    const float* bb[3]   = {(const float*)d_in[7],  (const float*)d_in[14], (const float*)d_in[21]};
    const float* Wt[3]   = {(const float*)d_in[8],  (const float*)d_in[15], (const float*)d_in[22]};
    const float* bt[3]   = {(const float*)d_in[9],  (const float*)d_in[16], (const float*)d_in[23]};
    const float* pv[3]   = {(const float*)d_in[10], (const float*)d_in[17], (const float*)d_in[24]};
    const float* Wl1 = (const float*)d_in[25];
    const float* bl1 = (const float*)d_in[26];
    const float* Wl2 = (const float*)d_in[27];
    const float* bl2 = (const float*)d_in[28];
    float* out = (float*)d_out;

    const bool batched = ws_size >= (size_t)225 * 1024 * 1024;

    char* wp = (char*)d_ws;
    auto carve = [&](size_t bytes) -> void* {
        void* p = (void*)wp;
        wp += (bytes + 255) & ~(size_t)255;
        return p;
    };
    const int NMAX = 12800;
    const int GKMAX = 10240;
    const size_t MSZ = (size_t)CC * CC;
    const int NSLOT = batched ? 9 : 3;
    unsigned short* A2H = (unsigned short*)carve((size_t)GKMAX * HC3 * 2);  // 62.9 MB
    unsigned short* A2L = (unsigned short*)carve((size_t)GKMAX * HC3 * 2);  // 62.9 MB
    // weight temps alias into A2 (prep completes before aggregate_sel writes A2)
    unsigned short* WTH = (unsigned short*)A2H;
    unsigned short* WTL = WTH + (size_t)NSLOT * MSZ;
    unsigned short* WSH = WTL + (size_t)NSLOT * MSZ;
    unsigned short* WSL = (unsigned short*)A2L;
    float* XN   = (float*)carve((size_t)GKMAX * CC * 4); // 41.9 MB
    unsigned short* B2H = (unsigned short*)carve((size_t)NSLOT * MSZ * 2);
    unsigned short* B2L = (unsigned short*)carve((size_t)NSLOT * MSZ * 2);
    float* PM   = (float*)carve((size_t)NG * 8 * CC * 4);
    float* PS   = (float*)carve((size_t)NG * 8 * CC * 4);
    float* ASV  = (float*)carve((size_t)3 * HC3 * 4);
    float* ADV  = (float*)carve((size_t)3 * HC3 * 4);
    float* QV   = (float*)carve((size_t)3 * HC3 * 4);
    float* UU   = (float*)carve((size_t)3 * HC3 * 4);
    float* BV   = (float*)carve((size_t)3 * CC * 4);
    float* AS   = (float*)carve((size_t)NMAX * 3 * 4);
    float* AD   = (float*)carve((size_t)NMAX * 3 * 4);
    float* T3   = (float*)carve((size_t)NMAX * 3 * 4);
    float* SL   = (float*)carve((size_t)NMAX * 3 * 4);
    unsigned* MXE = (unsigned*)carve((size_t)NMAX * 3 * 4);
    float* SEXP = (float*)carve((size_t)NMAX * 3 * 4);
    int* CNT    = (int*)carve((size_t)NMAX * 4);
    int* NEWID  = (int*)carve((size_t)NMAX * 4);
    int* CSRS   = (int*)carve((size_t)NMAX * MAXDEG * 4);  // 3.3 MB
    int* SRC = (int*)carve((size_t)EE * 4);
    int* DST = (int*)carve((size_t)EE * 4);
    int* MK  = (int*)carve((size_t)EE * 4);
    int* PERM  = (int*)carve((size_t)GKMAX * 4);
    float* VALS = (float*)carve((size_t)GKMAX * 4);
    float* PN  = (float*)carve(256);
    float* BVP = (float*)carve(256);
    float* R0 = (float*)carve((size_t)NG * 2048 * 4);
    float* R1 = (float*)carve((size_t)NG * 2048 * 4);
    float* R2 = (float*)carve((size_t)NG * 2048 * 4);
    float* Z1 = (float*)carve((size_t)NG * 1024 * 4);
    float* Rarr[3] = {R0, R1, R2};
    (void)in_sizes; (void)n_in; (void)out_size;

    copy_edges<<<cdiv(EE, 256), 256, 0, stream>>>(ei, SRC, DST, MK);

    auto prep = [&](int lbase, int nl) {
        int nslots = 3 * nl;
        split_w_all<<<dim3(4096, nslots), 256, 0, stream>>>(W[0], W[1], W[2], lbase, WSH, WSL);
        transpose_split_wt_all<<<dim3(32, 32, nslots), 256, 0, stream>>>(Wt[0], Wt[1], Wt[2],
                                                                          lbase, WTH, WTL);
        wtp_all<<<nl * 768, 256, 0, stream>>>(Wt[0], Wt[1], Wt[2], pv[0], pv[1], pv[2],
                                              lbase, UU);
        gemm_prep<<<dim3(8, 8, nslots), 256, 0, stream>>>(WTH, WTL, WSH, WSL, B2H, B2L, CC);
        attvec_all<<<dim3(768, nl), 256, 0, stream>>>(W[0], W[1], W[2],
            atts[0], atts[1], atts[2], attd[0], attd[1], attd[2], UU, lbase, ASV, ADV, QV);
        bvinit_pnorm<<<dim3(5, nl), 256, 0, stream>>>(bt[0], bt[1], bt[2],
            pv[0], pv[1], pv[2], lbase, BV, PN);
        bvec_part<<<dim3(4, 12, nl), 256, 0, stream>>>(bb[0], bb[1], bb[2],
            Wt[0], Wt[1], Wt[2], lbase, BV);
        bvp_all<<<nl, 256, 0, stream>>>(BV, pv[0], pv[1], pv[2], lbase, BVP);
    };

    if (batched) prep(0, 3);

    const int ns_[3]  = {12800, 10240, 5120};
    const int npg_[3] = {200, 160, 80};
    const int kk_[3]  = {160, 80, 16};
    const int sk_[3]  = {2, 2, 4};     // split-K factors
    const float* xin = x;

    for (int L = 0; L < 3; ++L) {
        int n = ns_[L], npg = npg_[L], k = kk_[L];
        int gk = NG * k;
        if (!batched) prep(L, 1);
        size_t b2off = batched ? (size_t)L * 3 * MSZ : 0;
        attn_node<<<n / 4, 256, 0, stream>>>(xin, ASV + (size_t)L * HC3,
            ADV + (size_t)L * HC3, QV + (size_t)L * HC3, AS, AD, T3,
            SL, MXE, SEXP, CNT, n);
        edge_pass1<<<cdiv(EE, 256), 256, 0, stream>>>(SRC, DST, MK,
            (L > 0) ? NEWID : (const int*)nullptr, AS, AD, MXE, SEXP, CNT, CSRS);
        score_topk<<<NG, 64, 0, stream>>>(T3, SL, MXE, SEXP, AS, AD, CNT, CSRS,
                                          BVP + L, PN + L, npg, k, PERM, VALS, NEWID);
        aggregate_sel<<<gk, 256, 0, stream>>>(xin, SL, MXE, SEXP, AS, AD, CNT, CSRS,
                                              PERM, A2H, A2L);
        hipMemsetAsync(XN, 0, (size_t)gk * CC * 4, stream);
        gemm_splitk<<<dim3(gk / 128, 8, sk_[L]), 256, 0, stream>>>(A2H, A2L, HC3,
            B2H + b2off, B2L + b2off, HC3, XN, CC, HC3 / sk_[L]);
        readout_part<<<dim3(NG, 8), 256, 0, stream>>>(XN, BV + (size_t)L * CC, VALS,
                                                      k, PM, PS);
        readout_fin<<<NG, 256, 0, stream>>>(PM, PS, k, Rarr[L]);
        xin = XN;
    }

    // final MLP
    mlp1_kernel<<<dim3(4, NG), 256, 0, stream>>>(R0, R1, R2, Wl1, bl1, Z1);
    mlp2_kernel<<<NG * 2, 64, 0, stream>>>(Z1, Wl2, bl2, out);
}